// Round 11
// baseline (1086.524 us; speedup 1.0000x reference)
//
#include <hip/hip_runtime.h>

// GNNCASimple — fused per-node pipeline (bf16 MFMA, fp32 accum), fp32 I/O.
// Step s: xform: p = relu(h@W_pre+b_pre)   [LDS, buffer shared with m]
//                m = relu(p@W_conv+b_conv) [same LDS buffer, WAR barrier]
//                pw2 = p@Wp2 (fused), q = m@Wz
//         agg:   zq = segsum(q[src]); h' = bf16(zq+pw2+b_post)  (fp32 out at last step)
// r10: operand-swapped MFMAs — mfma(W_frag, act_frag) gives D[outcol][node] so each
// thread holds 4 CONSECUTIVE out-cols of one node: LDS epilogues are ds_write_b64
// (vs r8's 128 ds_write_b16/wave — LDS-pipe co-bottleneck), pw2 = dwordx4, q rows
// written by a single wave (fixes r8's 2x write amplification without r9's scalar
// scatter regression). agg = r8 version.

#define NN 100000
#define NPAD 100064
#define FS 64
#define HH 256
#define NE 1600000
#define NSTEPS 4
#define GA 128                    // fillA blocks
#define EPB (NE / GA)             // 12500 edges per fillA block
#define BK2SH 9                   // log2(nodes per coarse bucket)
#define NBK2 ((NN + 511) / 512)   // 196 buckets

typedef unsigned short u16;
typedef unsigned int u32;
typedef __attribute__((ext_vector_type(8))) short bfrag;   // 8 bf16 = 4 VGPRs (MFMA A/B)
typedef __attribute__((ext_vector_type(4))) float ffrag;   // 4 fp32 (MFMA C/D)

static __device__ __forceinline__ float4 ld4(const float* p) { return *(const float4*)p; }
static __device__ __forceinline__ u16 f2bf(float f) {  // RNE
    union { float f; u32 u; } v; v.f = f;
    return (u16)((v.u + 0x7fffu + ((v.u >> 16) & 1u)) >> 16);
}
static __device__ __forceinline__ float bf2f(u16 h) {
    union { u32 u; float f; } v; v.u = (u32)h << 16; return v.f;
}
static __device__ __forceinline__ u32 pack2bf(float a, float b) {
    return (u32)f2bf(a) | ((u32)f2bf(b) << 16);
}

// ---------------- x (fp32) -> hbf (bf16) ----------------
__global__ void cvt_x_k(const float4* __restrict__ x, uint2* __restrict__ hbf, int n4) {
    int i = blockIdx.x * 256 + threadIdx.x;
    if (i < n4) {
        float4 v = x[i];
        hbf[i] = make_uint2(pack2bf(v.x, v.y), pack2bf(v.z, v.w));
    }
}

// ---------------- W [K][C] fp32 -> Wt [C][K] bf16 ----------------
template <int LK, int LC>
__global__ void transpose_cvt_k(const float* __restrict__ W, u16* __restrict__ Wt) {
    const int K = 1 << LK, C = 1 << LC;
    int i = blockIdx.x * 256 + threadIdx.x;
    if (i < K * C) {
        int c = i >> LK, k = i & (K - 1);
        Wt[i] = f2bf(W[(size_t)k * C + c]);
    }
}

// ---------------- offsets: per-node histogram + scan ----------------
__global__ void zero_int_k(int* __restrict__ p, int n) {
    int i = blockIdx.x * 256 + threadIdx.x;
    if (i < n) p[i] = 0;
}

__global__ void hist_k(const int* __restrict__ dst, int* __restrict__ cnt) {
    int e = blockIdx.x * 256 + threadIdx.x;
    if (e < NE) atomicAdd(&cnt[dst[e]], 1);   // no-return atomics: cheap (r4/r5 evidence)
}

__global__ void scan1_k(const int* __restrict__ cnt, int* __restrict__ part, int* __restrict__ sums) {
    __shared__ int sh[256];
    const int t = threadIdx.x;
    const int base = blockIdx.x * 1024 + t * 4;
    int v0 = (base + 0 < NN) ? cnt[base + 0] : 0;
    int v1 = (base + 1 < NN) ? cnt[base + 1] : 0;
    int v2 = (base + 2 < NN) ? cnt[base + 2] : 0;
    int v3 = (base + 3 < NN) ? cnt[base + 3] : 0;
    int s = v0 + v1 + v2 + v3;
    sh[t] = s;
    __syncthreads();
    for (int o = 1; o < 256; o <<= 1) {
        int y = (t >= o) ? sh[t - o] : 0;
        __syncthreads();
        sh[t] += y;
        __syncthreads();
    }
    int ex = sh[t] - s;
    if (base + 0 < NN) part[base + 0] = ex; ex += v0;
    if (base + 1 < NN) part[base + 1] = ex; ex += v1;
    if (base + 2 < NN) part[base + 2] = ex; ex += v2;
    if (base + 3 < NN) part[base + 3] = ex;
    if (t == 0) sums[blockIdx.x] = sh[255];
}

__global__ void scan2_k(int* __restrict__ sums, int nb) {
    __shared__ int sh[128];
    const int t = threadIdx.x;
    int v = (t < nb) ? sums[t] : 0;
    sh[t] = v;
    __syncthreads();
    for (int o = 1; o < 128; o <<= 1) {
        int y = (t >= o) ? sh[t - o] : 0;
        __syncthreads();
        sh[t] += y;
        __syncthreads();
    }
    if (t < nb) sums[t] = sh[t] - v;
}

__global__ void scan3_k(int* __restrict__ offsets, const int* __restrict__ sums) {
    int i = blockIdx.x * 256 + threadIdx.x;
    if (i < NN) offsets[i] += sums[i >> 10];
}

__global__ void final_off_k(int* __restrict__ offsets) {
    if (threadIdx.x == 0) offsets[NN] = NE;
}

// ---------------- fillA: group edges into per-block private segments by coarse bucket ----------------
__global__ __launch_bounds__(256) void fillA_k(const int* __restrict__ dst, const int* __restrict__ src,
                                               int* __restrict__ cntM, int* __restrict__ offM,  // [NBK2][GA]
                                               uint2* __restrict__ tmp) {
    __shared__ int cnt[256];
    __shared__ int sc[256];
    __shared__ int cur[256];
    const int t = threadIdx.x, b = blockIdx.x;
    const int e0 = b * EPB;
    cnt[t] = 0;
    __syncthreads();
    for (int i = t; i < EPB; i += 256) atomicAdd(&cnt[dst[e0 + i] >> BK2SH], 1);
    __syncthreads();
    int v = cnt[t];
    sc[t] = v;
    __syncthreads();
    for (int o = 1; o < 256; o <<= 1) {
        int y = (t >= o) ? sc[t - o] : 0;
        __syncthreads();
        sc[t] += y;
        __syncthreads();
    }
    int excl = sc[t] - v;
    cur[t] = excl;
    if (t < NBK2) {
        cntM[t * GA + b] = v;
        offM[t * GA + b] = excl;
    }
    __syncthreads();
    uint2* seg = tmp + (size_t)b * EPB;
    for (int i = t; i < EPB; i += 256) {
        int d = dst[e0 + i], s = src[e0 + i];
        int pos = atomicAdd(&cur[d >> BK2SH], 1);
        seg[pos] = make_uint2((u32)d, (u32)s);
    }
}

// ---------------- fillB: one block per bucket; scatter srcs into contiguous window ----------------
__global__ __launch_bounds__(256) void fillB_k(const uint2* __restrict__ tmp,
                                               const int* __restrict__ cntM, const int* __restrict__ offM,
                                               const int* __restrict__ offsets, int* __restrict__ srcs) {
    __shared__ int cur[512];
    __shared__ int runlen[GA];
    __shared__ int runoff[GA];
    const int t = threadIdx.x, k = blockIdx.x;
    const int nodeBase = k << BK2SH;
    for (int i = t; i < 512; i += 256) {
        int node = nodeBase + i;
        cur[i] = (node < NN) ? offsets[node] : 0;
    }
    if (t < GA) {
        runlen[t] = cntM[k * GA + t];
        runoff[t] = offM[k * GA + t];
    }
    __syncthreads();
    const int rsub = t >> 6;     // 4 runs processed concurrently (one per wave)
    const int elane = t & 63;
    for (int g = 0; g < GA / 4; g++) {
        int rb = g * 4 + rsub;
        int len = runlen[rb];
        const uint2* run = tmp + (size_t)rb * EPB + runoff[rb];
        for (int e = elane; e < len; e += 64) {
            uint2 ed = run[e];
            int pos = atomicAdd(&cur[(int)ed.x - nodeBase], 1);
            srcs[pos] = (int)ed.y;
        }
    }
}

// ---------------- fused node transform (64-node tiles, shared p/m LDS, swapped MFMA) ----------------
// All MFMAs: mfma(W_frag, act_frag) -> D[outcol][node]; thread (l16,quad) holds
// node=l16 (of a 16-node tile) and out-cols quad*4..quad*4+3 (consecutive!).
__global__ __launch_bounds__(256, 4) void xform_k(const u16* __restrict__ hbf,     // [NPAD][64]
                                                  const u16* __restrict__ Wpt,     // [256][64]
                                                  const float* __restrict__ b_pre,
                                                  const u16* __restrict__ Wct,     // [256][256]
                                                  const float* __restrict__ b_conv,
                                                  const u16* __restrict__ Wzt,     // [64][256]
                                                  const u16* __restrict__ Wp2t,    // [64][256]
                                                  u16* __restrict__ qbf,           // [NN][64]
                                                  float* __restrict__ pw2o) {      // [NPAD][64]
    __shared__ u16 ts[64 * 264];   // p tile, then m tile (bf16, stride 264)
    const int t = threadIdx.x;
    const int wave = t >> 6, lane = t & 63;
    const int quad = lane >> 4, l16 = lane & 15;
    const int nodeBase = blockIdx.x * 64;

    // ---- stage 1: p = relu(h @ W_pre + b_pre) -> ts; wave w owns p-cols [64w,64w+64) ----
    {
        ffrag acc[4][4];   // [pcol-tile nt][node-tile mt]
#pragma unroll
        for (int nt = 0; nt < 4; nt++)
#pragma unroll
            for (int mt = 0; mt < 4; mt++) acc[nt][mt] = (ffrag)0.f;
#pragma unroll
        for (int ch = 0; ch < 2; ch++) {
            const int kb = ch * 32 + quad * 8;
            bfrag w[4], h[4];
#pragma unroll
            for (int nt = 0; nt < 4; nt++)
                w[nt] = *(const bfrag*)(Wpt + (size_t)(wave * 64 + nt * 16 + l16) * FS + kb);
#pragma unroll
            for (int mt = 0; mt < 4; mt++)
                h[mt] = *(const bfrag*)(hbf + (size_t)(nodeBase + mt * 16 + l16) * FS + kb);
#pragma unroll
            for (int nt = 0; nt < 4; nt++)
#pragma unroll
                for (int mt = 0; mt < 4; mt++)
                    acc[nt][mt] = __builtin_amdgcn_mfma_f32_16x16x32_bf16(w[nt], h[mt], acc[nt][mt], 0, 0, 0);
        }
#pragma unroll
        for (int nt = 0; nt < 4; nt++) {
            const int colBase = wave * 64 + nt * 16 + quad * 4;
            const float4 bv = ld4(b_pre + colBase);
#pragma unroll
            for (int mt = 0; mt < 4; mt++) {
                uint2 pk;
                pk.x = pack2bf(fmaxf(acc[nt][mt][0] + bv.x, 0.f), fmaxf(acc[nt][mt][1] + bv.y, 0.f));
                pk.y = pack2bf(fmaxf(acc[nt][mt][2] + bv.z, 0.f), fmaxf(acc[nt][mt][3] + bv.w, 0.f));
                *(uint2*)&ts[(mt * 16 + l16) * 264 + colBase] = pk;   // ds_write_b64
            }
        }
    }
    __syncthreads();   // #1: p visible

    // ---- stage 2: m = relu(p @ W_conv + b_conv) [regs], pw2 = p @ Wp2 (fused) ----
    ffrag accm[4][4];  // [mcol-tile i][node-tile j]
    ffrag accw[4];     // [pw2col-tile ct], nodes = wave's 16-node tile
    {
#pragma unroll
        for (int i = 0; i < 4; i++) {
            accw[i] = (ffrag)0.f;
#pragma unroll
            for (int j = 0; j < 4; j++) accm[i][j] = (ffrag)0.f;
        }
#pragma unroll
        for (int ch = 0; ch < 8; ch++) {
            const int kb = ch * 32 + quad * 8;
            bfrag wc[4], pb[4], wp[4];
#pragma unroll
            for (int i = 0; i < 4; i++)
                wc[i] = *(const bfrag*)(Wct + (size_t)(wave * 64 + i * 16 + l16) * HH + kb);
#pragma unroll
            for (int j = 0; j < 4; j++)
                pb[j] = *(const bfrag*)(ts + (j * 16 + l16) * 264 + kb);
#pragma unroll
            for (int ct = 0; ct < 4; ct++)
                wp[ct] = *(const bfrag*)(Wp2t + (size_t)(ct * 16 + l16) * HH + kb);
#pragma unroll
            for (int i = 0; i < 4; i++)
#pragma unroll
                for (int j = 0; j < 4; j++)
                    accm[i][j] = __builtin_amdgcn_mfma_f32_16x16x32_bf16(wc[i], pb[j], accm[i][j], 0, 0, 0);
#pragma unroll
            for (int ct = 0; ct < 4; ct++)
                accw[ct] = __builtin_amdgcn_mfma_f32_16x16x32_bf16(wp[ct], pb[wave], accw[ct], 0, 0, 0);
        }
    }
    __syncthreads();   // #2: all p reads done (WAR before m overwrites ts)

    // ---- write m -> ts (b64), pw2 -> global (dwordx4, rows owned by one wave) ----
    {
#pragma unroll
        for (int i = 0; i < 4; i++) {
            const int colBase = wave * 64 + i * 16 + quad * 4;
            const float4 bv = ld4(b_conv + colBase);
#pragma unroll
            for (int j = 0; j < 4; j++) {
                uint2 pk;
                pk.x = pack2bf(fmaxf(accm[i][j][0] + bv.x, 0.f), fmaxf(accm[i][j][1] + bv.y, 0.f));
                pk.y = pack2bf(fmaxf(accm[i][j][2] + bv.z, 0.f), fmaxf(accm[i][j][3] + bv.w, 0.f));
                *(uint2*)&ts[(j * 16 + l16) * 264 + colBase] = pk;
            }
        }
        const int node = nodeBase + wave * 16 + l16;
        if (node < NN) {
#pragma unroll
            for (int ct = 0; ct < 4; ct++)
                *(ffrag*)&pw2o[(size_t)node * FS + ct * 16 + quad * 4] = accw[ct];
        }
    }
    __syncthreads();   // #3: m visible

    // ---- stage 3: q = m @ Wz (q rows owned by one wave) ----
    {
        ffrag qa[4];
#pragma unroll
        for (int ct = 0; ct < 4; ct++) qa[ct] = (ffrag)0.f;
#pragma unroll
        for (int ch = 0; ch < 8; ch++) {
            const int kb = ch * 32 + quad * 8;
            bfrag mb = *(const bfrag*)(ts + (wave * 16 + l16) * 264 + kb);
#pragma unroll
            for (int ct = 0; ct < 4; ct++) {
                bfrag wz = *(const bfrag*)(Wzt + (size_t)(ct * 16 + l16) * HH + kb);
                qa[ct] = __builtin_amdgcn_mfma_f32_16x16x32_bf16(wz, mb, qa[ct], 0, 0, 0);
            }
        }
        const int node = nodeBase + wave * 16 + l16;
        if (node < NN) {
#pragma unroll
            for (int ct = 0; ct < 4; ct++) {
                uint2 pk;
                pk.x = pack2bf(qa[ct][0], qa[ct][1]);
                pk.y = pack2bf(qa[ct][2], qa[ct][3]);
                *(uint2*)&qbf[(size_t)node * FS + ct * 16 + quad * 4] = pk;
            }
        }
    }
}

// ---------------- aggregation + h-build (r8 version) ----------------
__global__ __launch_bounds__(256) void agg_k(const u32* __restrict__ q2,  // [NN][32] packed bf16 pairs
                                             const int* __restrict__ offsets,
                                             const int* __restrict__ srcs,
                                             const float* __restrict__ pw2,
                                             const float* __restrict__ b_post,
                                             u32* __restrict__ hbf_out,   // [NPAD][32] packed (steps 0..2)
                                             float* __restrict__ outf) {  // [NN][64] (last step)
    const int wave = threadIdx.x >> 6;
    const int lane = threadIdx.x & 63;
    const int node = blockIdx.x * 4 + wave;
    const int half = lane >> 5, c = lane & 31;
    const int beg = offsets[node], end = offsets[node + 1];
    float ax = 0.f, ay = 0.f, bx = 0.f, by = 0.f;
    int e = beg + half;
    for (; e + 6 < end; e += 8) {
        int s0 = srcs[e], s1 = srcs[e + 2], s2 = srcs[e + 4], s3 = srcs[e + 6];
        u32 g0 = q2[(size_t)s0 * 32 + c];
        u32 g1 = q2[(size_t)s1 * 32 + c];
        u32 g2 = q2[(size_t)s2 * 32 + c];
        u32 g3 = q2[(size_t)s3 * 32 + c];
        ax += bf2f((u16)g0) + bf2f((u16)g1);
        ay += bf2f((u16)(g0 >> 16)) + bf2f((u16)(g1 >> 16));
        bx += bf2f((u16)g2) + bf2f((u16)g3);
        by += bf2f((u16)(g2 >> 16)) + bf2f((u16)(g3 >> 16));
    }
    for (; e < end; e += 2) {
        u32 g = q2[(size_t)srcs[e] * 32 + c];
        ax += bf2f((u16)g);
        ay += bf2f((u16)(g >> 16));
    }
    ax += bx; ay += by;
    ax += __shfl_xor(ax, 32);
    ay += __shfl_xor(ay, 32);
    if (half == 0) {
        float2 w = *(const float2*)&pw2[(size_t)node * FS + 2 * c];
        float2 b = *(const float2*)&b_post[2 * c];
        float hx = ax + w.x + b.x;
        float hy = ay + w.y + b.y;
        if (outf) {
            *(float2*)&outf[(size_t)node * FS + 2 * c] = make_float2(hx, hy);
        } else {
            hbf_out[(size_t)node * 32 + c] = pack2bf(hx, hy);
        }
    }
}

extern "C" void kernel_launch(void* const* d_in, const int* in_sizes, int n_in,
                              void* d_out, int out_size, void* d_ws, size_t ws_size,
                              hipStream_t stream) {
    const float* x      = (const float*)d_in[0];
    const int*   ei     = (const int*)d_in[1];
    const float* W_pre  = (const float*)d_in[2];
    const float* b_pre  = (const float*)d_in[3];
    const float* W_conv = (const float*)d_in[4];
    const float* b_conv = (const float*)d_in[5];
    const float* W_post = (const float*)d_in[6];
    const float* b_post = (const float*)d_in[7];
    float* out = (float*)d_out;

    char* ws = (char*)d_ws;
    size_t off = 0;
    auto alloc = [&](size_t bytes) -> char* {
        char* r = ws + off;
        off += (bytes + 255) & ~(size_t)255;
        return r;
    };
    u16* hbf     = (u16*)alloc((size_t)NPAD * FS * 2);    // 12.8 MB
    u16* qbf     = (u16*)alloc((size_t)NN * FS * 2);      // 12.8 MB
    float* pw2   = (float*)alloc((size_t)NPAD * FS * 4);  // 25.6 MB
    uint2* tmp   = (uint2*)alloc((size_t)NE * 8);         // 12.8 MB
    int* offsets = (int*)alloc((size_t)(NN + 1) * 4);
    int* cnt     = (int*)alloc((size_t)NN * 4);
    int* srcs    = (int*)alloc((size_t)NE * 4);           //  6.4 MB
    int* sums    = (int*)alloc(128 * 4);
    int* cntM    = (int*)alloc((size_t)NBK2 * GA * 4);    // 100 KB
    int* offM    = (int*)alloc((size_t)NBK2 * GA * 4);    // 100 KB
    u16* Wpt     = (u16*)alloc((size_t)HH * FS * 2);      // [256][64]
    u16* Wct     = (u16*)alloc((size_t)HH * HH * 2);      // [256][256]
    u16* Wzt     = (u16*)alloc((size_t)FS * HH * 2);      // [64][256]
    u16* Wp2t    = (u16*)alloc((size_t)FS * HH * 2);      // [64][256]
    (void)ws_size; (void)in_sizes; (void)n_in; (void)out_size;

    const int* dst = ei;       // edge_index[0] = aggregation targets
    const int* src = ei + NE;  // edge_index[1] = message sources

    // input casts / weight transposes
    cvt_x_k<<<(NN * FS / 4 + 255) / 256, 256, 0, stream>>>((const float4*)x, (uint2*)hbf, NN * FS / 4);
    transpose_cvt_k<6, 8><<<(HH * FS + 255) / 256, 256, 0, stream>>>(W_pre, Wpt);
    transpose_cvt_k<8, 8><<<(HH * HH + 255) / 256, 256, 0, stream>>>(W_conv, Wct);
    transpose_cvt_k<8, 6><<<(HH * FS + 255) / 256, 256, 0, stream>>>(W_post, Wzt);
    transpose_cvt_k<8, 6><<<(HH * FS + 255) / 256, 256, 0, stream>>>(W_post + HH * FS, Wp2t);

    // offsets (per-node histogram + hierarchical scan)
    zero_int_k<<<(NN + 255) / 256, 256, 0, stream>>>(cnt, NN);
    hist_k<<<(NE + 255) / 256, 256, 0, stream>>>(dst, cnt);
    const int NB = (NN + 1023) / 1024;  // 98
    scan1_k<<<NB, 256, 0, stream>>>(cnt, offsets, sums);
    scan2_k<<<1, 128, 0, stream>>>(sums, NB);
    scan3_k<<<(NN + 255) / 256, 256, 0, stream>>>(offsets, sums);
    final_off_k<<<1, 64, 0, stream>>>(offsets);

    // srcs permutation (two-phase local-group scatter)
    fillA_k<<<GA, 256, 0, stream>>>(dst, src, cntM, offM, tmp);
    fillB_k<<<NBK2, 256, 0, stream>>>(tmp, cntM, offM, offsets, srcs);

    const int GB = (NN + 63) / 64;  // 1563
    for (int s = 0; s < NSTEPS; s++) {
        xform_k<<<GB, 256, 0, stream>>>(hbf, Wpt, b_pre, Wct, b_conv, Wzt, Wp2t, qbf, pw2);
        if (s < NSTEPS - 1)
            agg_k<<<NN / 4, 256, 0, stream>>>((const u32*)qbf, offsets, srcs, pw2, b_post,
                                              (u32*)hbf, nullptr);
        else
            agg_k<<<NN / 4, 256, 0, stream>>>((const u32*)qbf, offsets, srcs, pw2, b_post,
                                              nullptr, out);
    }
}

// Round 12
// 641.557 us; speedup vs baseline: 1.6936x; 1.6936x over previous
//
#include <hip/hip_runtime.h>

// GNNCASimple — fused per-node pipeline (bf16 MFMA, fp32 accum), fp32 I/O.
// Step s: xform: p = relu(h@W_pre+b_pre)   [LDS, buffer shared with m]
//                m = relu(p@W_conv+b_conv) [same LDS buffer, WAR barrier]
//                pw2 = p@Wp2 (fused), q = m@Wz
//         agg:   zq = segsum(q[src]); h' = bf16(zq+pw2+b_post)  (fp32 out at last step)
// xform/agg = r8 versions (75us xform — r7 32-tile, r9 row-scatter, r10 swapped-MFMA
// all regressed; r10 showed 8x write amplification from 16B node-strided stores).
// r11: CSR streamlined — fillA packs (dst,src) into u32 (9b local|23b src), fillB
// computes per-node offsets in LDS (kills zero/hist/scan1/scan2/scan3 kernels).

#define NN 100000
#define NPAD 100064
#define FS 64
#define HH 256
#define NE 1600000
#define NSTEPS 4
#define GA 128                    // fillA blocks
#define EPB (NE / GA)             // 12500 edges per fillA block
#define BK2SH 9                   // log2(nodes per coarse bucket)
#define BS2 (1 << BK2SH)          // 512
#define NBK2 ((NN + BS2 - 1) / BS2)   // 196 buckets

typedef unsigned short u16;
typedef unsigned int u32;
typedef __attribute__((ext_vector_type(8))) short bfrag;   // 8 bf16 = 4 VGPRs (MFMA A/B)
typedef __attribute__((ext_vector_type(4))) float ffrag;   // 4 fp32 (MFMA C/D)

static __device__ __forceinline__ u16 f2bf(float f) {  // RNE
    union { float f; u32 u; } v; v.f = f;
    return (u16)((v.u + 0x7fffu + ((v.u >> 16) & 1u)) >> 16);
}
static __device__ __forceinline__ float bf2f(u16 h) {
    union { u32 u; float f; } v; v.u = (u32)h << 16; return v.f;
}
static __device__ __forceinline__ u32 pack2bf(float a, float b) {
    return (u32)f2bf(a) | ((u32)f2bf(b) << 16);
}

// ---------------- x (fp32) -> hbf (bf16) ----------------
__global__ void cvt_x_k(const float4* __restrict__ x, uint2* __restrict__ hbf, int n4) {
    int i = blockIdx.x * 256 + threadIdx.x;
    if (i < n4) {
        float4 v = x[i];
        hbf[i] = make_uint2(pack2bf(v.x, v.y), pack2bf(v.z, v.w));
    }
}

// ---------------- all weight transposes (fp32 [K][C] -> bf16 [C][K]) in one launch ----------------
__global__ void prep_w_k(const float* __restrict__ W_pre, const float* __restrict__ W_conv,
                         const float* __restrict__ W_post,
                         u16* __restrict__ Wpt, u16* __restrict__ Wct,
                         u16* __restrict__ Wzt, u16* __restrict__ Wp2t) {
    int i = blockIdx.x * 256 + threadIdx.x;
    if (i < 65536) {                       // Wct [256][256] <- W_conv [256][256]
        int c = i >> 8, k = i & 255;
        Wct[i] = f2bf(W_conv[k * HH + c]);
    } else if (i < 81920) {                // Wpt [256][64] <- W_pre [64][256]
        int j = i - 65536;
        int c = j >> 6, k = j & 63;
        Wpt[j] = f2bf(W_pre[k * HH + c]);
    } else if (i < 98304) {                // Wzt [64][256] <- W_post rows [0,256)
        int j = i - 81920;
        int c = j >> 8, k = j & 255;
        Wzt[j] = f2bf(W_post[k * FS + c]);
    } else if (i < 114688) {               // Wp2t [64][256] <- W_post rows [256,512)
        int j = i - 98304;
        int c = j >> 8, k = j & 255;
        Wp2t[j] = f2bf(W_post[(HH + k) * FS + c]);
    }
}

// ---------------- fillA: group packed edges into per-block private segments by bucket ----------------
__global__ __launch_bounds__(256) void fillA_k(const int* __restrict__ dst, const int* __restrict__ src,
                                               int* __restrict__ cntM, int* __restrict__ offM,  // [NBK2][GA]
                                               u32* __restrict__ tmp) {
    __shared__ int cnt[256];
    __shared__ int sc[256];
    __shared__ int cur[256];
    const int t = threadIdx.x, b = blockIdx.x;
    const int e0 = b * EPB;
    cnt[t] = 0;
    __syncthreads();
    for (int i = t; i < EPB; i += 256) atomicAdd(&cnt[dst[e0 + i] >> BK2SH], 1);
    __syncthreads();
    int v = cnt[t];
    sc[t] = v;
    __syncthreads();
    for (int o = 1; o < 256; o <<= 1) {
        int y = (t >= o) ? sc[t - o] : 0;
        __syncthreads();
        sc[t] += y;
        __syncthreads();
    }
    int excl = sc[t] - v;
    cur[t] = excl;
    if (t < NBK2) {
        cntM[t * GA + b] = v;
        offM[t * GA + b] = excl;
    }
    __syncthreads();
    u32* seg = tmp + (size_t)b * EPB;
    for (int i = t; i < EPB; i += 256) {
        int d = dst[e0 + i], s = src[e0 + i];
        int pos = atomicAdd(&cur[d >> BK2SH], 1);
        seg[pos] = ((u32)(d & (BS2 - 1)) << 23) | (u32)s;   // 9b local node | 23b src
    }
}

// ---------------- bscan: bucket totals from cntM + exclusive scan -> bstart ----------------
__global__ void bscan_k(const int* __restrict__ cntM, int* __restrict__ bstart) {
    __shared__ int sh[256];
    const int t = threadIdx.x;
    int tot = 0;
    if (t < NBK2)
        for (int b = 0; b < GA; b++) tot += cntM[t * GA + b];
    sh[t] = tot;
    __syncthreads();
    for (int o = 1; o < 256; o <<= 1) {
        int y = (t >= o) ? sh[t - o] : 0;
        __syncthreads();
        sh[t] += y;
        __syncthreads();
    }
    if (t < NBK2) bstart[t] = sh[t] - tot;
    if (t == 255) bstart[NBK2] = sh[255];  // == NE
}

// ---------------- fillB: one block per bucket; computes offsets AND scatters srcs ----------------
__global__ __launch_bounds__(256) void fillB_k(const u32* __restrict__ tmp,
                                               const int* __restrict__ cntM, const int* __restrict__ offM,
                                               const int* __restrict__ bstart,
                                               int* __restrict__ offsets, int* __restrict__ srcs) {
    __shared__ int cnt[BS2];
    __shared__ int cur[BS2];
    __shared__ int runlen[GA];
    __shared__ int runoff[GA];
    const int t = threadIdx.x, k = blockIdx.x;
    const int nodeBase = k << BK2SH;
    cnt[t] = 0;
    cnt[t + 256] = 0;
    if (t < GA) {
        runlen[t] = cntM[k * GA + t];
        runoff[t] = offM[k * GA + t];
    }
    __syncthreads();
    const int rsub = t >> 6;
    const int elane = t & 63;
    // pass 1: per-node counts
    for (int g = 0; g < GA / 4; g++) {
        int rb = g * 4 + rsub;
        int len = runlen[rb];
        const u32* run = tmp + (size_t)rb * EPB + runoff[rb];
        for (int e = elane; e < len; e += 64) atomicAdd(&cnt[run[e] >> 23], 1);
    }
    __syncthreads();
    // scan 512 counters with 256 threads (sequential pairs + Hillis-Steele on pair sums)
    int a = cnt[2 * t], b2 = cnt[2 * t + 1];
    int s = a + b2;
    cur[t] = s;
    __syncthreads();
    for (int o = 1; o < 256; o <<= 1) {
        int y = (t >= o) ? cur[t - o] : 0;
        __syncthreads();
        cur[t] += y;
        __syncthreads();
    }
    int exclPair = cur[t] - s;
    __syncthreads();   // everyone done reading cur as scan array
    const int base = bstart[k];
    int o0 = base + exclPair;
    int o1 = o0 + a;
    int n0 = nodeBase + 2 * t, n1 = n0 + 1;
    if (n0 < NN) offsets[n0] = o0;
    if (n1 < NN) offsets[n1] = o1;
    cur[2 * t] = o0;
    cur[2 * t + 1] = o1;
    __syncthreads();
    // pass 2: scatter src into contiguous window (cache-hot)
    for (int g = 0; g < GA / 4; g++) {
        int rb = g * 4 + rsub;
        int len = runlen[rb];
        const u32* run = tmp + (size_t)rb * EPB + runoff[rb];
        for (int e = elane; e < len; e += 64) {
            u32 p = run[e];
            int pos = atomicAdd(&cur[p >> 23], 1);
            srcs[pos] = (int)(p & 0x7FFFFFu);
        }
    }
}

__global__ void final_off_k(int* __restrict__ offsets) {
    if (threadIdx.x == 0) offsets[NN] = NE;
}

// ---------------- fused node transform (r8 version — 64-node tiles, shared p/m LDS) ----------------
__global__ __launch_bounds__(256, 4) void xform_k(const u16* __restrict__ hbf,     // [NPAD][64]
                                                  const u16* __restrict__ Wpt,     // [256][64]
                                                  const float* __restrict__ b_pre,
                                                  const u16* __restrict__ Wct,     // [256][256]
                                                  const float* __restrict__ b_conv,
                                                  const u16* __restrict__ Wzt,     // [64][256]
                                                  const u16* __restrict__ Wp2t,    // [64][256]
                                                  u16* __restrict__ qbf,           // [NN][64]
                                                  float* __restrict__ pw2o) {      // [NPAD][64]
    __shared__ u16 ts[64 * 264];   // p tile, then m tile (bf16, stride 264)
    const int t = threadIdx.x;
    const int wave = t >> 6, lane = t & 63;
    const int quad = lane >> 4, l16 = lane & 15;
    const int nodeBase = blockIdx.x * 64;

    // ---- stage 1: p = relu(h @ W_pre + b_pre) -> ts ----
    {
        ffrag acc[4][4];
#pragma unroll
        for (int mt = 0; mt < 4; mt++)
#pragma unroll
            for (int nt = 0; nt < 4; nt++) acc[mt][nt] = (ffrag)0.f;
#pragma unroll
        for (int ch = 0; ch < 2; ch++) {
            const int kb = ch * 32 + quad * 8;
            bfrag a[4], b[4];
#pragma unroll
            for (int mt = 0; mt < 4; mt++)
                a[mt] = *(const bfrag*)(hbf + (size_t)(nodeBase + mt * 16 + l16) * FS + kb);
#pragma unroll
            for (int nt = 0; nt < 4; nt++)
                b[nt] = *(const bfrag*)(Wpt + (size_t)(wave * 64 + nt * 16 + l16) * FS + kb);
#pragma unroll
            for (int mt = 0; mt < 4; mt++)
#pragma unroll
                for (int nt = 0; nt < 4; nt++)
                    acc[mt][nt] = __builtin_amdgcn_mfma_f32_16x16x32_bf16(a[mt], b[nt], acc[mt][nt], 0, 0, 0);
        }
#pragma unroll
        for (int nt = 0; nt < 4; nt++) {
            const int col = wave * 64 + nt * 16 + l16;
            const float bv = b_pre[col];
#pragma unroll
            for (int mt = 0; mt < 4; mt++)
#pragma unroll
                for (int r = 0; r < 4; r++)
                    ts[(mt * 16 + quad * 4 + r) * 264 + col] = f2bf(fmaxf(acc[mt][nt][r] + bv, 0.f));
        }
    }
    __syncthreads();   // #1: p visible

    // ---- stage 2: m = relu(p @ W_conv + b_conv) [regs], pw2 = p @ Wp2 (fused) ----
    ffrag accm[4][4];
    ffrag accw[4];
    {
#pragma unroll
        for (int mt = 0; mt < 4; mt++) {
            accw[mt] = (ffrag)0.f;
#pragma unroll
            for (int nt = 0; nt < 4; nt++) accm[mt][nt] = (ffrag)0.f;
        }
#pragma unroll
        for (int ch = 0; ch < 8; ch++) {
            const int kb = ch * 32 + quad * 8;
            bfrag a[4], b[4], bw;
#pragma unroll
            for (int mt = 0; mt < 4; mt++)
                a[mt] = *(const bfrag*)(ts + (mt * 16 + l16) * 264 + kb);
#pragma unroll
            for (int nt = 0; nt < 4; nt++)
                b[nt] = *(const bfrag*)(Wct + (size_t)(wave * 64 + nt * 16 + l16) * HH + kb);
            bw = *(const bfrag*)(Wp2t + (size_t)(wave * 16 + l16) * HH + kb);
#pragma unroll
            for (int mt = 0; mt < 4; mt++) {
#pragma unroll
                for (int nt = 0; nt < 4; nt++)
                    accm[mt][nt] = __builtin_amdgcn_mfma_f32_16x16x32_bf16(a[mt], b[nt], accm[mt][nt], 0, 0, 0);
                accw[mt] = __builtin_amdgcn_mfma_f32_16x16x32_bf16(a[mt], bw, accw[mt], 0, 0, 0);
            }
        }
    }
    __syncthreads();   // #2: all p reads done (WAR before m overwrites ts)

    // ---- write m -> ts, pw2 -> global ----
    {
#pragma unroll
        for (int nt = 0; nt < 4; nt++) {
            const int col = wave * 64 + nt * 16 + l16;
            const float bv = b_conv[col];
#pragma unroll
            for (int mt = 0; mt < 4; mt++)
#pragma unroll
                for (int r = 0; r < 4; r++)
                    ts[(mt * 16 + quad * 4 + r) * 264 + col] = f2bf(fmaxf(accm[mt][nt][r] + bv, 0.f));
        }
        const int colw = wave * 16 + l16;
#pragma unroll
        for (int mt = 0; mt < 4; mt++)
#pragma unroll
            for (int r = 0; r < 4; r++) {
                int node = nodeBase + mt * 16 + quad * 4 + r;
                if (node < NN) pw2o[(size_t)node * FS + colw] = accw[mt][r];
            }
    }
    __syncthreads();   // #3: m visible

    // ---- stage 3: q = m @ Wz ----
    {
        ffrag qa[4];
#pragma unroll
        for (int mt = 0; mt < 4; mt++) qa[mt] = (ffrag)0.f;
#pragma unroll
        for (int ch = 0; ch < 8; ch++) {
            const int kb = ch * 32 + quad * 8;
            bfrag bz = *(const bfrag*)(Wzt + (size_t)(wave * 16 + l16) * HH + kb);
#pragma unroll
            for (int mt = 0; mt < 4; mt++) {
                bfrag am = *(const bfrag*)(ts + (mt * 16 + l16) * 264 + kb);
                qa[mt] = __builtin_amdgcn_mfma_f32_16x16x32_bf16(am, bz, qa[mt], 0, 0, 0);
            }
        }
        const int col = wave * 16 + l16;
#pragma unroll
        for (int mt = 0; mt < 4; mt++)
#pragma unroll
            for (int r = 0; r < 4; r++) {
                int node = nodeBase + mt * 16 + quad * 4 + r;
                if (node < NN) qbf[(size_t)node * FS + col] = f2bf(qa[mt][r]);
            }
    }
}

// ---------------- aggregation + h-build (r8 version) ----------------
__global__ __launch_bounds__(256) void agg_k(const u32* __restrict__ q2,  // [NN][32] packed bf16 pairs
                                             const int* __restrict__ offsets,
                                             const int* __restrict__ srcs,
                                             const float* __restrict__ pw2,
                                             const float* __restrict__ b_post,
                                             u32* __restrict__ hbf_out,   // [NPAD][32] packed (steps 0..2)
                                             float* __restrict__ outf) {  // [NN][64] (last step)
    const int wave = threadIdx.x >> 6;
    const int lane = threadIdx.x & 63;
    const int node = blockIdx.x * 4 + wave;
    const int half = lane >> 5, c = lane & 31;
    const int beg = offsets[node], end = offsets[node + 1];
    float ax = 0.f, ay = 0.f, bx = 0.f, by = 0.f;
    int e = beg + half;
    for (; e + 6 < end; e += 8) {
        int s0 = srcs[e], s1 = srcs[e + 2], s2 = srcs[e + 4], s3 = srcs[e + 6];
        u32 g0 = q2[(size_t)s0 * 32 + c];
        u32 g1 = q2[(size_t)s1 * 32 + c];
        u32 g2 = q2[(size_t)s2 * 32 + c];
        u32 g3 = q2[(size_t)s3 * 32 + c];
        ax += bf2f((u16)g0) + bf2f((u16)g1);
        ay += bf2f((u16)(g0 >> 16)) + bf2f((u16)(g1 >> 16));
        bx += bf2f((u16)g2) + bf2f((u16)g3);
        by += bf2f((u16)(g2 >> 16)) + bf2f((u16)(g3 >> 16));
    }
    for (; e < end; e += 2) {
        u32 g = q2[(size_t)srcs[e] * 32 + c];
        ax += bf2f((u16)g);
        ay += bf2f((u16)(g >> 16));
    }
    ax += bx; ay += by;
    ax += __shfl_xor(ax, 32);
    ay += __shfl_xor(ay, 32);
    if (half == 0) {
        float2 w = *(const float2*)&pw2[(size_t)node * FS + 2 * c];
        float2 b = *(const float2*)&b_post[2 * c];
        float hx = ax + w.x + b.x;
        float hy = ay + w.y + b.y;
        if (outf) {
            *(float2*)&outf[(size_t)node * FS + 2 * c] = make_float2(hx, hy);
        } else {
            hbf_out[(size_t)node * 32 + c] = pack2bf(hx, hy);
        }
    }
}

extern "C" void kernel_launch(void* const* d_in, const int* in_sizes, int n_in,
                              void* d_out, int out_size, void* d_ws, size_t ws_size,
                              hipStream_t stream) {
    const float* x      = (const float*)d_in[0];
    const int*   ei     = (const int*)d_in[1];
    const float* W_pre  = (const float*)d_in[2];
    const float* b_pre  = (const float*)d_in[3];
    const float* W_conv = (const float*)d_in[4];
    const float* b_conv = (const float*)d_in[5];
    const float* W_post = (const float*)d_in[6];
    const float* b_post = (const float*)d_in[7];
    float* out = (float*)d_out;

    char* ws = (char*)d_ws;
    size_t off = 0;
    auto alloc = [&](size_t bytes) -> char* {
        char* r = ws + off;
        off += (bytes + 255) & ~(size_t)255;
        return r;
    };
    u16* hbf     = (u16*)alloc((size_t)NPAD * FS * 2);    // 12.8 MB
    u16* qbf     = (u16*)alloc((size_t)NN * FS * 2);      // 12.8 MB
    float* pw2   = (float*)alloc((size_t)NPAD * FS * 4);  // 25.6 MB
    u32* tmp     = (u32*)alloc((size_t)NE * 4);           //  6.4 MB
    int* offsets = (int*)alloc((size_t)(NN + 1) * 4);
    int* srcs    = (int*)alloc((size_t)NE * 4);           //  6.4 MB
    int* cntM    = (int*)alloc((size_t)NBK2 * GA * 4);    // 100 KB
    int* offM    = (int*)alloc((size_t)NBK2 * GA * 4);    // 100 KB
    int* bstart  = (int*)alloc((size_t)(NBK2 + 1) * 4);
    u16* Wpt     = (u16*)alloc((size_t)HH * FS * 2);      // [256][64]
    u16* Wct     = (u16*)alloc((size_t)HH * HH * 2);      // [256][256]
    u16* Wzt     = (u16*)alloc((size_t)FS * HH * 2);      // [64][256]
    u16* Wp2t    = (u16*)alloc((size_t)FS * HH * 2);      // [64][256]
    (void)ws_size; (void)in_sizes; (void)n_in; (void)out_size;

    const int* dst = ei;       // edge_index[0] = aggregation targets
    const int* src = ei + NE;  // edge_index[1] = message sources

    // input cast / weight transposes
    cvt_x_k<<<(NN * FS / 4 + 255) / 256, 256, 0, stream>>>((const float4*)x, (uint2*)hbf, NN * FS / 4);
    prep_w_k<<<448, 256, 0, stream>>>(W_pre, W_conv, W_post, Wpt, Wct, Wzt, Wp2t);

    // CSR build (fillA buckets -> bucket scan -> fillB offsets+scatter)
    fillA_k<<<GA, 256, 0, stream>>>(dst, src, cntM, offM, tmp);
    bscan_k<<<1, 256, 0, stream>>>(cntM, bstart);
    fillB_k<<<NBK2, 256, 0, stream>>>(tmp, cntM, offM, bstart, offsets, srcs);
    final_off_k<<<1, 64, 0, stream>>>(offsets);

    const int GB = (NN + 63) / 64;  // 1563
    for (int s = 0; s < NSTEPS; s++) {
        xform_k<<<GB, 256, 0, stream>>>(hbf, Wpt, b_pre, Wct, b_conv, Wzt, Wp2t, qbf, pw2);
        if (s < NSTEPS - 1)
            agg_k<<<NN / 4, 256, 0, stream>>>((const u32*)qbf, offsets, srcs, pw2, b_post,
                                              (u32*)hbf, nullptr);
        else
            agg_k<<<NN / 4, 256, 0, stream>>>((const u32*)qbf, offsets, srcs, pw2, b_post,
                                              nullptr, out);
    }
}